// Round 6
// baseline (179.927 us; speedup 1.0000x reference)
//
#include <hip/hip_runtime.h>

// NestedConv via MFMA bf16: B=64, N=128, D=64.
// out[b,i,j,:] = m[b,i,j] * sum_k A[b,k,j] * h[b,i,k,:]
// h = relu(relu((m*X)@W1+b1)@W2+b2),  A symmetric 0/1 (bf16-exact).
//
// Round-6: latency-bound fix -> per-wave MLP (memory-level parallelism).
//  - IPB=4 i-tiles per block; X/mask for i+1 issued at top of i's compute
//    (register prefetch; consumed one iteration later).
//  - raw s_barrier + manual lgkmcnt-only waits (hipcc drains vmcnt(0) at
//    __syncthreads, which would kill the prefetch).
//  - W1 fragments + biases hoisted out of the i-loop; phase-1 mask values
//    reused for the output store (identical row indexing in swapped form).
//  - H1 wave-private (no barrier around it); H2T guarded by 2 raw barriers.
#define Bv 64
#define Nv 128
#define Dv 64
#define IPB 4

// ws layout: [0,32KB): Wpk (16KB used). [32KB, 32KB+2MB): Apk.
#define APK_OFF_SH 16384
#define WS_NEED (32768 + Bv * 32768)

typedef __attribute__((ext_vector_type(8))) short bf16x8;
typedef __attribute__((ext_vector_type(4))) float f32x4;
typedef __attribute__((ext_vector_type(4))) unsigned u32x4;

// f32 -> bf16 RNE scalar (cold paths / pre-kernels)
__device__ __forceinline__ unsigned short f2bf(float f) {
    unsigned u = __float_as_uint(f);
    u += 0x7FFFu + ((u >> 16) & 1u);
    return (unsigned short)(u >> 16);
}
// packed f32x2 -> bf16x2 (hot paths)
__device__ __forceinline__ unsigned cvtpk(float lo, float hi) {
    unsigned r;
    asm("v_cvt_pk_bf16_f32 %0, %1, %2" : "=v"(r) : "v"(lo), "v"(hi));
    return r;
}
__device__ __forceinline__ bf16x8 pack8m(float4 a, float4 b, float m) {
    u32x4 pk;
    pk[0] = cvtpk(m * a.x, m * a.y);
    pk[1] = cvtpk(m * a.z, m * a.w);
    pk[2] = cvtpk(m * b.x, m * b.y);
    pk[3] = cvtpk(m * b.z, m * b.w);
    return __builtin_bit_cast(bf16x8, pk);
}
__device__ __forceinline__ bf16x8 pack8(float4 a, float4 b) {
    bf16x8 r;
    r[0] = (short)f2bf(a.x); r[1] = (short)f2bf(a.y);
    r[2] = (short)f2bf(a.z); r[3] = (short)f2bf(a.w);
    r[4] = (short)f2bf(b.x); r[5] = (short)f2bf(b.y);
    r[6] = (short)f2bf(b.z); r[7] = (short)f2bf(b.w);
    return r;
}
__device__ __forceinline__ uint2 relu_pk4(f32x4 v) {
    return make_uint2(cvtpk(fmaxf(v[0], 0.f), fmaxf(v[1], 0.f)),
                      cvtpk(fmaxf(v[2], 0.f), fmaxf(v[3], 0.f)));
}
// fallback W fragment loader (PRE=false only)
__device__ __forceinline__ bf16x8 load_w_frag(const float* __restrict__ W,
                                              int kkbase, int dn, int l15, int l16) {
    const float* p = W + (kkbase + 8 * l16) * Dv + dn + l15;
    bf16x8 r;
    #pragma unroll
    for (int t = 0; t < 8; ++t) r[t] = (short)f2bf(p[t * Dv]);
    return r;
}

// ---- pre-kernel: pack W1,W2 fragments ----
// Wpk[f][l][t], f = layer*8 + kk*4 + tn; value = W[kk*32+8*(l>>4)+t][tn*16+(l&15)]
__global__ void pack_w_kernel(const float* __restrict__ W1,
                              const float* __restrict__ W2,
                              unsigned short* __restrict__ wpk) {
    const int idx = blockIdx.x * 256 + threadIdx.x;   // 1024 items
    const int l = idx & 63, f = idx >> 6;
    const int layer = f >> 3, kk = (f >> 2) & 1, tn = f & 3;
    const float* W = layer ? W2 : W1;
    const float* p = W + (kk * 32 + 8 * (l >> 4)) * Dv + tn * 16 + (l & 15);
    unsigned short* o = wpk + f * 512 + l * 8;
    #pragma unroll
    for (int t = 0; t < 8; ++t) o[t] = f2bf(p[t * Dv]);
}

// ---- pre-kernel: pack A fragments ----
// Apk[b][jt][kk][l][t] = A[b][jt*16+(l&15)][kk*32+8*(l>>4)+t]
__global__ void pack_a_kernel(const float* __restrict__ A,
                              unsigned short* __restrict__ apk) {
    const int gid = blockIdx.x * 256 + threadIdx.x;   // 131072 items
    const int l = gid & 63, f = gid >> 6;             // f = b*32 + jt*4 + kk
    const int b = f >> 5, r = f & 31, jt = r >> 2, kk = r & 3;
    const float4* p = (const float4*)(A +
        ((size_t)(b * Nv + jt * 16 + (l & 15))) * Nv + kk * 32 + 8 * (l >> 4));
    *(bf16x8*)(apk + (size_t)f * 512 + l * 8) = pack8(p[0], p[1]);
}

template <bool PRE>
__global__ __launch_bounds__(256, 3)
void nested_conv_mfma(const float* __restrict__ X,
                      const float* __restrict__ A,
                      const int*   __restrict__ mask,
                      const float* __restrict__ W1,
                      const float* __restrict__ b1,
                      const float* __restrict__ W2,
                      const float* __restrict__ b2,
                      const unsigned short* __restrict__ wpk,
                      const unsigned short* __restrict__ apk,
                      float* __restrict__ out)
{
    __shared__ __align__(16) unsigned char H1[16384];   // [128 r][64 d] bf16 swizzled (wave-private rows)
    __shared__ __align__(16) unsigned char H2T[16384];  // [64 d][128 k] bf16 swizzled

    const int bx = blockIdx.x, b = blockIdx.y;
    const int tid = threadIdx.x;
    const int l = tid & 63, w = tid >> 6, l15 = l & 15, l16 = l >> 4;
    const int i0 = bx * IPB;

    float4 xb[2][8];   // X prefetch double-buffer (statically indexed; loop fully unrolled)
    float  mv[2][2];   // mask double-buffer

#define ISSUE_LOADS(I, SEL) do {                                                 \
        const size_t bi_ = (size_t)(b * Nv + (I));                               \
        _Pragma("unroll")                                                        \
        for (int rr_ = 0; rr_ < 2; ++rr_) {                                      \
            const int r_ = (2 * w + rr_) * 16 + l15;                             \
            mv[SEL][rr_] = mask[bi_ * Nv + r_] ? 1.0f : 0.0f;                    \
            const float4* xp_ = (const float4*)(X + (bi_ * Nv + r_) * Dv + 8 * l16); \
            xb[SEL][rr_ * 4 + 0] = xp_[0];                                       \
            xb[SEL][rr_ * 4 + 1] = xp_[1];                                       \
            xb[SEL][rr_ * 4 + 2] = xp_[8];                                       \
            xb[SEL][rr_ * 4 + 3] = xp_[9];                                       \
        }                                                                        \
    } while (0)

    // fire the first X/mask loads before anything else (HBM latency)
    ISSUE_LOADS(i0, 0);

    // hoisted loop-invariants (L2-hot; overlap with the X loads above)
    bf16x8 w1f[2][4];
    #pragma unroll
    for (int kk = 0; kk < 2; ++kk)
        #pragma unroll
        for (int dt = 0; dt < 4; ++dt)
            w1f[kk][dt] = PRE ? *(const bf16x8*)(wpk + (kk * 4 + dt) * 512 + l * 8)
                              : load_w_frag(W1, kk * 32, dt * 16, l15, l16);
    float4 b1v[4];
    #pragma unroll
    for (int dt = 0; dt < 4; ++dt) b1v[dt] = *(const float4*)&b1[dt * 16 + 4 * l16];
    float b2v[4];
    #pragma unroll
    for (int tn = 0; tn < 4; ++tn) b2v[tn] = b2[tn * 16 + l15];

    const unsigned short* Apb = apk + (size_t)b * 32 * 512;

    #pragma unroll
    for (int it = 0; it < IPB; ++it) {
        const int cur = it & 1, nxt = cur ^ 1;
        const int i = i0 + it;
        const size_t bi = (size_t)(b * Nv + i);

        // prefetch next i-tile (consumed one iteration later; hidden under this
        // iteration's compute — no vmcnt drain at the raw barriers below)
        if (it + 1 < IPB) ISSUE_LOADS(i + 1, nxt);

        // ===== layer 1 (swapped): H1T-tiles = W1T @ XmT =====
        f32x4 acc1[2][4];
        #pragma unroll
        for (int dt = 0; dt < 4; ++dt) {
            acc1[0][dt] = (f32x4){b1v[dt].x, b1v[dt].y, b1v[dt].z, b1v[dt].w};
            acc1[1][dt] = acc1[0][dt];
        }
        #pragma unroll
        for (int kk = 0; kk < 2; ++kk) {
            bf16x8 xf[2];
            #pragma unroll
            for (int rr = 0; rr < 2; ++rr)
                xf[rr] = pack8m(xb[cur][rr * 4 + kk * 2], xb[cur][rr * 4 + kk * 2 + 1],
                                mv[cur][rr]);
            #pragma unroll
            for (int dt = 0; dt < 4; ++dt) {
                acc1[0][dt] = __builtin_amdgcn_mfma_f32_16x16x32_bf16(w1f[kk][dt], xf[0], acc1[0][dt], 0, 0, 0);
                acc1[1][dt] = __builtin_amdgcn_mfma_f32_16x16x32_bf16(w1f[kk][dt], xf[1], acc1[1][dt], 0, 0, 0);
            }
        }
        // H1[r][d] writes (8B, swizzled); wave-private rows -> no barrier
        #pragma unroll
        for (int rr = 0; rr < 2; ++rr) {
            const int r = (2 * w + rr) * 16 + l15;
            #pragma unroll
            for (int dt = 0; dt < 4; ++dt) {
                const int bo   = dt * 32 + l16 * 8;
                const int addr = r * 128 + (((bo & ~15) ^ ((r & 7) << 4)) | (bo & 15));
                *(uint2*)&H1[addr] = relu_pk4(acc1[rr][dt]);
            }
        }
        // H1 fragment reads (same wave; lgkm-ordered by compiler)
        bf16x8 h1f[2][2];
        #pragma unroll
        for (int kk = 0; kk < 2; ++kk)
            #pragma unroll
            for (int rr = 0; rr < 2; ++rr) {
                const int r = (2 * w + rr) * 16 + l15;
                h1f[kk][rr] = *(const bf16x8*)&H1[r * 128 + ((kk * 64 + 16 * l16) ^ ((r & 7) << 4))];
            }

        // ===== layer 2 (normal): H2 = relu(H1 @ W2 + b2) =====
        f32x4 acc2[2][4];
        #pragma unroll
        for (int tn = 0; tn < 4; ++tn) {
            acc2[0][tn] = (f32x4){b2v[tn], b2v[tn], b2v[tn], b2v[tn]};
            acc2[1][tn] = acc2[0][tn];
        }
        #pragma unroll
        for (int kk = 0; kk < 2; ++kk)
            #pragma unroll
            for (int tn = 0; tn < 4; ++tn) {
                const bf16x8 wf = PRE
                    ? *(const bf16x8*)(wpk + (8 + kk * 4 + tn) * 512 + l * 8)
                    : load_w_frag(W2, kk * 32, tn * 16, l15, l16);
                acc2[0][tn] = __builtin_amdgcn_mfma_f32_16x16x32_bf16(h1f[kk][0], wf, acc2[0][tn], 0, 0, 0);
                acc2[1][tn] = __builtin_amdgcn_mfma_f32_16x16x32_bf16(h1f[kk][1], wf, acc2[1][tn], 0, 0, 0);
            }
        // H2T[d][k] writes (8B, swizzled)
        #pragma unroll
        for (int rr = 0; rr < 2; ++rr)
            #pragma unroll
            for (int tn = 0; tn < 4; ++tn) {
                const int d    = tn * 16 + l15;
                const int bo   = (2 * w + rr) * 32 + l16 * 8;
                const int addr = d * 256 + (((bo & ~15) ^ ((d & 7) << 4)) | (bo & 15));
                *(uint2*)&H2T[addr] = relu_pk4(acc2[rr][tn]);
            }
        // barrier A: H2T writes drained (lgkm only — X prefetch stays in flight)
        asm volatile("s_waitcnt lgkmcnt(0)" ::: "memory");
        __builtin_amdgcn_s_barrier();
        asm volatile("" ::: "memory");

        // ===== phase 2 (swapped): outT-tiles = H2T @ A_b =====
        f32x4 accO[2][4];
        #pragma unroll
        for (int jj = 0; jj < 2; ++jj)
            #pragma unroll
            for (int dt = 0; dt < 4; ++dt)
                accO[jj][dt] = (f32x4){0.f, 0.f, 0.f, 0.f};
        #pragma unroll
        for (int kk = 0; kk < 4; ++kk) {
            bf16x8 anf[2];
            #pragma unroll
            for (int jj = 0; jj < 2; ++jj) {
                const int jt = 2 * w + jj;
                if (PRE) {
                    anf[jj] = *(const bf16x8*)(Apb + (jt * 4 + kk) * 512 + l * 8);
                } else {
                    const float4* ap = (const float4*)(A +
                        ((size_t)b * Nv + jt * 16 + l15) * Nv + kk * 32 + 8 * l16);
                    anf[jj] = pack8(ap[0], ap[1]);
                }
            }
            #pragma unroll
            for (int dt = 0; dt < 4; ++dt) {
                const int d = dt * 16 + l15;
                const bf16x8 hf = *(const bf16x8*)&H2T[d * 256 + ((kk * 64 + 16 * l16) ^ ((d & 7) << 4))];
                accO[0][dt] = __builtin_amdgcn_mfma_f32_16x16x32_bf16(hf, anf[0], accO[0][dt], 0, 0, 0);
                accO[1][dt] = __builtin_amdgcn_mfma_f32_16x16x32_bf16(hf, anf[1], accO[1][dt], 0, 0, 0);
            }
        }
        // barrier B: all waves' H2T reads retired before next iter's writes
        if (it + 1 < IPB) {
            asm volatile("s_waitcnt lgkmcnt(0)" ::: "memory");
            __builtin_amdgcn_s_barrier();
            asm volatile("" ::: "memory");
        }

        // ---- out store (mask reused from phase-1: same row indexing) ----
        float* Ob = out + bi * Nv * Dv;
        #pragma unroll
        for (int jj = 0; jj < 2; ++jj) {
            const int j = (2 * w + jj) * 16 + l15;
            const float msk = mv[cur][jj];
            float* orow = Ob + (size_t)j * Dv + 4 * l16;
            #pragma unroll
            for (int dt = 0; dt < 4; ++dt) {
                const f32x4 v = accO[jj][dt];
                *(float4*)&orow[dt * 16] = make_float4(v[0] * msk, v[1] * msk,
                                                       v[2] * msk, v[3] * msk);
            }
        }
    }
#undef ISSUE_LOADS
}

extern "C" void kernel_launch(void* const* d_in, const int* in_sizes, int n_in,
                              void* d_out, int out_size, void* d_ws, size_t ws_size,
                              hipStream_t stream) {
    const float* X    = (const float*)d_in[0];
    const float* A    = (const float*)d_in[1];
    const int*   mask = (const int*)d_in[2];
    const float* W1   = (const float*)d_in[3];
    const float* b1   = (const float*)d_in[4];
    const float* W2   = (const float*)d_in[5];
    const float* b2   = (const float*)d_in[6];
    float* out = (float*)d_out;

    dim3 grid(Nv / IPB, Bv);   // blocks sharing b adjacent -> A[b]/Apk[b] L2-hot

    if (ws_size >= (size_t)WS_NEED) {
        unsigned short* wpk = (unsigned short*)d_ws;
        unsigned short* apk = wpk + APK_OFF_SH;
        pack_w_kernel<<<4, 256, 0, stream>>>(W1, W2, wpk);
        pack_a_kernel<<<512, 256, 0, stream>>>(A, apk);
        nested_conv_mfma<true><<<grid, 256, 0, stream>>>(
            X, A, mask, W1, b1, W2, b2, wpk, apk, out);
    } else {
        nested_conv_mfma<false><<<grid, 256, 0, stream>>>(
            X, A, mask, W1, b1, W2, b2, nullptr, nullptr, out);
    }
}

// Round 7
// 166.491 us; speedup vs baseline: 1.0807x; 1.0807x over previous
//
#include <hip/hip_runtime.h>

// NestedConv via MFMA bf16, wave-independent design. B=64, N=128, D=64.
// out[b,i,j,:] = m[b,i,j] * sum_k A[b,k,j] * h[b,i,k,:]
// h = relu(relu((m*X)@W1+b1)@W2+b2),  A symmetric 0/1 (bf16-exact).
//
// Round-7: ONE WAVE = ONE (b,i). Zero LDS, zero barriers.
//  - 32x32x16 MFMA everywhere. C-layout -> next-A-operand redistribution is a
//    single v_permlane32_swap_b32 per dword pair (one lane-bit exchange):
//    per K-subtile kt: swap(R[qa],R[qb]) -> (frag_lo, frag_hi), qa=(2kt)&3.
//  - phases: L1 (swapped, H1T = W1T @ XmT), L2 (normal, H2 = H1@W2),
//    P2 (swapped, outT = H2T @ A_b). All handoffs in registers.
//  - W1/W2/A pre-packed into 32x32-fragment order in d_ws (wpk 16KB: L1-hot;
//    apk 2MB: L2-hot per b).
#define Bv 64
#define Nv 128
#define Dv 64

#define APK_OFF_SH 16384            // shorts (= 32 KB bytes)
#define WS_NEED (32768 + Bv * 32768)

typedef __attribute__((ext_vector_type(8)))  short    bf16x8;
typedef __attribute__((ext_vector_type(16))) float    f32x16;
typedef __attribute__((ext_vector_type(4)))  unsigned u32x4;

__device__ __forceinline__ unsigned short f2bf(float f) {
    unsigned u = __float_as_uint(f);
    u += 0x7FFFu + ((u >> 16) & 1u);
    return (unsigned short)(u >> 16);
}
__device__ __forceinline__ unsigned cvtpk(float lo, float hi) {
    unsigned r;
    asm("v_cvt_pk_bf16_f32 %0, %1, %2" : "=v"(r) : "v"(lo), "v"(hi));
    return r;
}
// swap upper 32 lanes of d with lower 32 lanes of s:
// d' = {d.lo32lanes, s.lo32lanes}, s' = {d.hi32lanes, s.hi32lanes}
__device__ __forceinline__ void plswap(unsigned &d, unsigned &s) {
    asm("v_permlane32_swap_b32 %0, %1" : "+v"(d), "+v"(s));
}
__device__ __forceinline__ bf16x8 pack8m(float4 a, float4 b, float m) {
    u32x4 pk;
    pk[0] = cvtpk(m * a.x, m * a.y);
    pk[1] = cvtpk(m * a.z, m * a.w);
    pk[2] = cvtpk(m * b.x, m * b.y);
    pk[3] = cvtpk(m * b.z, m * b.w);
    return __builtin_bit_cast(bf16x8, pk);
}
__device__ __forceinline__ bf16x8 frag_from(uint2 lo, uint2 hi) {
    u32x4 u = {lo.x, lo.y, hi.x, hi.y};
    return __builtin_bit_cast(bf16x8, u);
}
// relu + pack 4 consecutive C regs (block q) -> 8 B
__device__ __forceinline__ uint2 rpk(const f32x16 a, int q) {
    return make_uint2(cvtpk(fmaxf(a[4*q+0], 0.f), fmaxf(a[4*q+1], 0.f)),
                      cvtpk(fmaxf(a[4*q+2], 0.f), fmaxf(a[4*q+3], 0.f)));
}
// fallback strided f32 fragment loader
__device__ __forceinline__ bf16x8 frag_strided(const float* p, int stride) {
    bf16x8 r;
    #pragma unroll
    for (int t = 0; t < 8; ++t) r[t] = (short)f2bf(p[t * stride]);
    return r;
}

// ---- pre-kernel: pack W1,W2 into 32x32-fragment order ----
// wpk[f][l][t], f = layer*8 + half*4 + kt:
//   value = W[kt*16 + 8*(l>>5) + t][half*32 + (l&31)]
__global__ void pack_w32(const float* __restrict__ W1,
                         const float* __restrict__ W2,
                         unsigned short* __restrict__ wpk) {
    const int idx = blockIdx.x * 256 + threadIdx.x;   // 1024
    const int l = idx & 63, f = idx >> 6;
    const int layer = f >> 3, half = (f >> 2) & 1, kt = f & 3;
    const float* W = layer ? W2 : W1;
    const float* p = W + (kt * 16 + 8 * (l >> 5)) * Dv + half * 32 + (l & 31);
    unsigned short* o = wpk + f * 512 + l * 8;
    #pragma unroll
    for (int t = 0; t < 8; ++t) o[t] = f2bf(p[t * Dv]);
}

// ---- pre-kernel: pack A into 32x32 B-fragment order ----
// apk[b][jt][kts][l][t] = A[b][j = jt*32+(l&31)][k = kts*16+8*(l>>5)+t]
// (A symmetric: A[j][k] == A[k][j]; row-j read gives contiguous k)
__global__ void pack_a32(const float* __restrict__ A,
                         unsigned short* __restrict__ apk) {
    const int gid = blockIdx.x * 256 + threadIdx.x;   // 131072
    const int l = gid & 63, f = gid >> 6;             // f = b*32 + jt*8 + kts
    const int b = f >> 5, r = f & 31, jt = r >> 3, kts = r & 7;
    const float4* p = (const float4*)(A + ((size_t)b * Nv + jt * 32 + (l & 31)) * Nv
                                        + kts * 16 + 8 * (l >> 5));
    const float4 v0 = p[0], v1 = p[1];
    u32x4 pk;
    pk[0] = (unsigned)f2bf(v0.x) | ((unsigned)f2bf(v0.y) << 16);
    pk[1] = (unsigned)f2bf(v0.z) | ((unsigned)f2bf(v0.w) << 16);
    pk[2] = (unsigned)f2bf(v1.x) | ((unsigned)f2bf(v1.y) << 16);
    pk[3] = (unsigned)f2bf(v1.z) | ((unsigned)f2bf(v1.w) << 16);
    *(u32x4*)(apk + (size_t)f * 512 + l * 8) = pk;
}

template <bool PRE>
__global__ __launch_bounds__(256, 2)
void nested_conv_wave(const float* __restrict__ X,
                      const float* __restrict__ A,
                      const int*   __restrict__ mask,
                      const float* __restrict__ W1,
                      const float* __restrict__ b1,
                      const float* __restrict__ W2,
                      const float* __restrict__ b2,
                      const unsigned short* __restrict__ wpk,
                      const unsigned short* __restrict__ apk,
                      float* __restrict__ out)
{
    const int tid = threadIdx.x;
    const int w   = tid >> 6;
    const int l   = tid & 63;
    const int l31 = l & 31;
    const int g   = l >> 5;            // lane half
    const int i   = blockIdx.x * 4 + w;    // global (b,ii): i = b*128 + ii
    const int b   = i >> 7;

    // mask row values for this lane's 4 row/col slots (r = j = rt*32 + l31)
    float mrow[4];
    #pragma unroll
    for (int rt = 0; rt < 4; ++rt)
        mrow[rt] = mask[(size_t)i * Nv + rt * 32 + l31] ? 1.0f : 0.0f;

    // biases: b1 expanded per C-row (d = dt2*32 + 8q + 4g + j); b2 per col
    float4 b1v[2][4];
    #pragma unroll
    for (int dt2 = 0; dt2 < 2; ++dt2)
        #pragma unroll
        for (int q = 0; q < 4; ++q)
            b1v[dt2][q] = *(const float4*)&b1[dt2 * 32 + q * 8 + g * 4];
    float b2v[2];
    #pragma unroll
    for (int nt = 0; nt < 2; ++nt) b2v[nt] = b2[nt * 32 + l31];

    // H2 packed: R2[nt][rt][q] = bf16x4 of H2[r = rt*32+8q+4g .. +3][d2 = nt*32+l31]
    uint2 R2[2][4][4];

    // ================= per r-tile: L1 + L2 =================
    #pragma unroll
    for (int rt = 0; rt < 4; ++rt) {
        // X fragment loads: XmT[k = kt*16+8g+t][r = l31]
        const float* xrow = X + ((size_t)i * Nv + rt * 32 + l31) * Dv + g * 8;
        float4 xv[4][2];
        #pragma unroll
        for (int kt = 0; kt < 4; ++kt) {
            const float4* xp = (const float4*)(xrow + kt * 16);
            xv[kt][0] = xp[0];
            xv[kt][1] = xp[1];
        }
        bf16x8 xf[4];
        #pragma unroll
        for (int kt = 0; kt < 4; ++kt)
            xf[kt] = pack8m(xv[kt][0], xv[kt][1], mrow[rt]);

        // ---- L1 (swapped): H1T[d][r] = sum_k W1[k][d] * Xm[r][k] ----
        f32x16 a1[2];
        #pragma unroll
        for (int dt2 = 0; dt2 < 2; ++dt2)
            #pragma unroll
            for (int q = 0; q < 4; ++q) {
                a1[dt2][4*q+0] = b1v[dt2][q].x;
                a1[dt2][4*q+1] = b1v[dt2][q].y;
                a1[dt2][4*q+2] = b1v[dt2][q].z;
                a1[dt2][4*q+3] = b1v[dt2][q].w;
            }
        #pragma unroll
        for (int kt = 0; kt < 4; ++kt)
            #pragma unroll
            for (int dt2 = 0; dt2 < 2; ++dt2) {
                const bf16x8 wf = PRE
                    ? *(const bf16x8*)(wpk + (size_t)(dt2 * 4 + kt) * 512 + l * 8)
                    : frag_strided(W1 + (kt*16 + 8*g) * Dv + dt2*32 + l31, Dv);
                a1[dt2] = __builtin_amdgcn_mfma_f32_32x32x16_bf16(wf, xf[kt], a1[dt2], 0, 0, 0);
            }

        // pack H1: R1[q][dt2] = bf16x4 of H1[r = l31][d = 32*dt2 + 8q + 4g .. +3]
        uint2 R1[4][2];
        #pragma unroll
        for (int dt2 = 0; dt2 < 2; ++dt2)
            #pragma unroll
            for (int q = 0; q < 4; ++q)
                R1[q][dt2] = rpk(a1[dt2], q);

        // redistribute -> L2 A-frags: frag(kt) = H1[r=l31][d = kt*16 + 8g + t]
        bf16x8 haf[4];
        #pragma unroll
        for (int kt = 0; kt < 4; ++kt) {
            const int dt2 = kt >> 1, qa = (2 * kt) & 3;
            plswap(R1[qa][dt2].x, R1[qa + 1][dt2].x);
            plswap(R1[qa][dt2].y, R1[qa + 1][dt2].y);
            haf[kt] = frag_from(R1[qa][dt2], R1[qa + 1][dt2]);
        }

        // ---- L2 (normal): H2[r][d2] = sum_d H1[r][d] * W2[d][d2] ----
        f32x16 a2[2];
        #pragma unroll
        for (int nt = 0; nt < 2; ++nt)
            #pragma unroll
            for (int e = 0; e < 16; ++e) a2[nt][e] = b2v[nt];
        #pragma unroll
        for (int kt = 0; kt < 4; ++kt)
            #pragma unroll
            for (int nt = 0; nt < 2; ++nt) {
                const bf16x8 wf = PRE
                    ? *(const bf16x8*)(wpk + (size_t)(8 + nt * 4 + kt) * 512 + l * 8)
                    : frag_strided(W2 + (kt*16 + 8*g) * Dv + nt*32 + l31, Dv);
                a2[nt] = __builtin_amdgcn_mfma_f32_32x32x16_bf16(haf[kt], wf, a2[nt], 0, 0, 0);
            }

        // pack H2 into R2
        #pragma unroll
        for (int nt = 0; nt < 2; ++nt)
            #pragma unroll
            for (int q = 0; q < 4; ++q)
                R2[nt][rt][q] = rpk(a2[nt], q);
    }

    // ================= P2 (swapped): outT[d2][j] = sum_k H2[k][d2] * A_b[k][j] =====
    // redistribute R2 in place -> A-frags: frag(dts,kts) = H2[k = kts*16+8g+t][d2 = dts*32+l31]
    #pragma unroll
    for (int dts = 0; dts < 2; ++dts)
        #pragma unroll
        for (int kts = 0; kts < 8; ++kts) {
            const int rt = kts >> 1, qa = (2 * kts) & 3;
            plswap(R2[dts][rt][qa].x, R2[dts][rt][qa + 1].x);
            plswap(R2[dts][rt][qa].y, R2[dts][rt][qa + 1].y);
        }

    const unsigned short* Apb = PRE ? apk + (size_t)b * 32 * 512 : nullptr;
    const float*          Ab  = A + (size_t)b * Nv * Nv;

    #pragma unroll
    for (int jt = 0; jt < 4; ++jt) {
        bf16x8 bfr[8];
        #pragma unroll
        for (int kts = 0; kts < 8; ++kts) {
            if (PRE) {
                bfr[kts] = *(const bf16x8*)(Apb + (size_t)(jt * 8 + kts) * 512 + l * 8);
            } else {
                const float4* ap = (const float4*)(Ab + ((size_t)jt * 32 + l31) * Nv
                                                     + kts * 16 + 8 * g);
                bfr[kts] = pack8m(ap[0], ap[1], 1.0f);
            }
        }
        f32x16 ao[2];
        #pragma unroll
        for (int dts = 0; dts < 2; ++dts)
            #pragma unroll
            for (int e = 0; e < 16; ++e) ao[dts][e] = 0.0f;
        #pragma unroll
        for (int kts = 0; kts < 8; ++kts) {
            const int rt = kts >> 1, qa = (2 * kts) & 3;
            #pragma unroll
            for (int dts = 0; dts < 2; ++dts) {
                const bf16x8 hf = frag_from(R2[dts][rt][qa], R2[dts][rt][qa + 1]);
                ao[dts] = __builtin_amdgcn_mfma_f32_32x32x16_bf16(hf, bfr[kts], ao[dts], 0, 0, 0);
            }
        }
        // store: out[i][j = jt*32+l31][d2 = dts*32 + 8q + 4g .. +3], masked
        const float msk = mrow[jt];
        float* orow = out + ((size_t)i * Nv + jt * 32 + l31) * Dv + g * 4;
        #pragma unroll
        for (int dts = 0; dts < 2; ++dts)
            #pragma unroll
            for (int q = 0; q < 4; ++q) {
                const float4 v = make_float4(ao[dts][4*q+0] * msk, ao[dts][4*q+1] * msk,
                                             ao[dts][4*q+2] * msk, ao[dts][4*q+3] * msk);
                *(float4*)&orow[dts * 32 + q * 8] = v;
            }
    }
}

extern "C" void kernel_launch(void* const* d_in, const int* in_sizes, int n_in,
                              void* d_out, int out_size, void* d_ws, size_t ws_size,
                              hipStream_t stream) {
    const float* X    = (const float*)d_in[0];
    const float* A    = (const float*)d_in[1];
    const int*   mask = (const int*)d_in[2];
    const float* W1   = (const float*)d_in[3];
    const float* b1   = (const float*)d_in[4];
    const float* W2   = (const float*)d_in[5];
    const float* b2   = (const float*)d_in[6];
    float* out = (float*)d_out;

    dim3 grid(Bv * Nv / 4);   // 2048 blocks x 4 waves, one wave per (b,i)

    if (ws_size >= (size_t)WS_NEED) {
        unsigned short* wpk = (unsigned short*)d_ws;
        unsigned short* apk = wpk + APK_OFF_SH;
        pack_w32<<<4, 256, 0, stream>>>(W1, W2, wpk);
        pack_a32<<<512, 256, 0, stream>>>(A, apk);
        nested_conv_wave<true><<<grid, 256, 0, stream>>>(
            X, A, mask, W1, b1, W2, b2, wpk, apk, out);
    } else {
        nested_conv_wave<false><<<grid, 256, 0, stream>>>(
            X, A, mask, W1, b1, W2, b2, nullptr, nullptr, out);
    }
}